// Round 2
// baseline (1980.535 us; speedup 1.0000x reference)
//
#include <hip/hip_runtime.h>
#include <cmath>

#define Bn   8
#define Cn   64
#define HWc  65536      // 256*256
#define HPc  246        // 256-11+1
#define HPWPc 60516     // 246*246
#define C1v  0.01f      // (0.01*10)^2
#define C2v  0.09f      // (0.03*10)^2

// 11-tap normalized gaussian, sigma=1.5 (double, then f32 cast — matches numpy)
static __device__ __forceinline__ void gauss11(float* gw) {
    double gg[11]; double s = 0.0;
#pragma unroll
    for (int j = 0; j < 11; ++j) { double d = (double)(j - 5); gg[j] = exp(-(d * d) / 4.5); s += gg[j]; }
#pragma unroll
    for (int j = 0; j < 11; ++j) gw[j] = (float)(gg[j] / s);
}

static __device__ __forceinline__ float4 f4z() { return make_float4(0.f, 0.f, 0.f, 0.f); }
static __device__ __forceinline__ float4 f4scale(float g, const float4 v) {
    return make_float4(g * v.x, g * v.y, g * v.z, g * v.w);
}
static __device__ __forceinline__ void f4add(float4& a, const float4 v) {
    a.x += v.x; a.y += v.y; a.z += v.z; a.w += v.w;
}
static __device__ __forceinline__ void f4fma(float4& a, const float4 u, const float4 v) {
    a.x = fmaf(u.x, v.x, a.x); a.y = fmaf(u.y, v.y, a.y);
    a.z = fmaf(u.z, v.z, a.z); a.w = fmaf(u.w, v.w, a.w);
}

// wave64 sum via DPP (VALU pipe, no LDS traffic). Result valid in lane 63.
static __device__ __forceinline__ float wave_sum64(float v) {
    v += __int_as_float(__builtin_amdgcn_update_dpp(0, __float_as_int(v), 0x111, 0xf, 0xf, true)); // row_shr:1
    v += __int_as_float(__builtin_amdgcn_update_dpp(0, __float_as_int(v), 0x112, 0xf, 0xf, true)); // row_shr:2
    v += __int_as_float(__builtin_amdgcn_update_dpp(0, __float_as_int(v), 0x114, 0xf, 0xf, true)); // row_shr:4
    v += __int_as_float(__builtin_amdgcn_update_dpp(0, __float_as_int(v), 0x118, 0xf, 0xf, true)); // row_shr:8
    v += __int_as_float(__builtin_amdgcn_update_dpp(0, __float_as_int(v), 0x142, 0xf, 0xf, true)); // row_bcast:15
    v += __int_as_float(__builtin_amdgcn_update_dpp(0, __float_as_int(v), 0x143, 0xf, 0xf, true)); // row_bcast:31
    return v;
}

// K1: channel max/mean/min (-> xcf planes, RAW) + masked stats atomics
__global__ __launch_bounds__(256) void k1_stats(const float* __restrict__ x, const int* __restrict__ mask,
                                                float* __restrict__ xcf, float* __restrict__ stats) {
    const int b = blockIdx.y;
    const int p0 = blockIdx.x * 1024 + threadIdx.x * 4;
    const float4* xp = (const float4*)(x + (size_t)b * Cn * HWc) + (p0 >> 2);
    float4 v = xp[0];
    float4 vmax = v, vmin = v, vsum = v;
#pragma unroll 4
    for (int c = 1; c < Cn; ++c) {
        float4 u = xp[(size_t)c * (HWc / 4)];
        vmax.x = fmaxf(vmax.x, u.x); vmax.y = fmaxf(vmax.y, u.y);
        vmax.z = fmaxf(vmax.z, u.z); vmax.w = fmaxf(vmax.w, u.w);
        vmin.x = fminf(vmin.x, u.x); vmin.y = fminf(vmin.y, u.y);
        vmin.z = fminf(vmin.z, u.z); vmin.w = fminf(vmin.w, u.w);
        vsum.x += u.x; vsum.y += u.y; vsum.z += u.z; vsum.w += u.w;
    }
    float4 vmean = make_float4(vsum.x * (1.f / 64.f), vsum.y * (1.f / 64.f),
                               vsum.z * (1.f / 64.f), vsum.w * (1.f / 64.f));
    *(float4*)(xcf + (size_t)(b * 3 + 0) * HWc + p0) = vmax;
    *(float4*)(xcf + (size_t)(b * 3 + 1) * HWc + p0) = vmean;
    *(float4*)(xcf + (size_t)(b * 3 + 2) * HWc + p0) = vmin;
    int4 mv = *(const int4*)(mask + (size_t)b * HWc + p0);
    float m0 = (float)mv.x, m1 = (float)mv.y, m2 = (float)mv.z, m3 = (float)mv.w;
    float r[7];
    r[0] = m0 + m1 + m2 + m3;
    r[1] = vmax.x * m0 + vmax.y * m1 + vmax.z * m2 + vmax.w * m3;
    r[2] = vmean.x * m0 + vmean.y * m1 + vmean.z * m2 + vmean.w * m3;
    r[3] = vmin.x * m0 + vmin.y * m1 + vmin.z * m2 + vmin.w * m3;
    r[4] = vmax.x * vmax.x * m0 + vmax.y * vmax.y * m1 + vmax.z * vmax.z * m2 + vmax.w * vmax.w * m3;
    r[5] = vmean.x * vmean.x * m0 + vmean.y * vmean.y * m1 + vmean.z * vmean.z * m2 + vmean.w * vmean.w * m3;
    r[6] = vmin.x * vmin.x * m0 + vmin.y * vmin.y * m1 + vmin.z * vmin.z * m2 + vmin.w * vmin.w * m3;
#pragma unroll
    for (int k = 0; k < 7; ++k) {
        float vv = wave_sum64(r[k]);
        if ((threadIdx.x & 63) == 63) atomicAdd(&stats[b * 8 + k], vv);
    }
}

// K4: mu_f = blur(xf), ef2 = blur(xf^2); xf computed inline from raw xc + mask + stats.
// Vertical pass from global (rowgroup 2, 176 threads), interleaved vb2, horizontal b128.
__global__ __launch_bounds__(256) void k4_blur3(const float* __restrict__ xc, const int* __restrict__ mask,
                                                const float* __restrict__ stats,
                                                float* __restrict__ muf, float* __restrict__ ef2g) {
    __shared__ __align__(16) float vb2[32 * 92];
    const int t = threadIdx.x;
    const int bi = blockIdx.z, b = bi / 3, i = bi % 3;
    const int y0 = blockIdx.y * 32, x0 = blockIdx.x * 32;
    float gw[11]; gauss11(gw);
    const float nst = stats[b * 8 + 0];
    const float s1 = stats[b * 8 + 1 + i], s2 = stats[b * 8 + 4 + i];
    const float mean = s1 / nst;
    const float rstd = rsqrtf((s2 - s1 * s1 / nst) / (nst - 1.0f));
    if (t < 176) {
        const int rg = t / 11, cg = t % 11, colo = cg * 4;
        const int gcb = min(x0 + colo, 252);
        const float* xp = xc + (size_t)bi * HWc;
        const int* mp = mask + (size_t)b * HWc;
        float4 av[2], ab[2];
#pragma unroll
        for (int r = 0; r < 2; ++r) { av[r] = f4z(); ab[r] = f4z(); }
#pragma unroll
        for (int k = 0; k < 12; ++k) {
            int gr = min(y0 + 2 * rg + k, 255);
            float4 v = *(const float4*)(xp + gr * 256 + gcb);
            int4 mv = *(const int4*)(mp + gr * 256 + gcb);
            float4 f;
            f.x = (v.x - mean) * rstd * (float)mv.x;
            f.y = (v.y - mean) * rstd * (float)mv.y;
            f.z = (v.z - mean) * rstd * (float)mv.z;
            f.w = (v.w - mean) * rstd * (float)mv.w;
            if (k <= 10) { float4 tv = f4scale(gw[k], f); f4add(av[0], tv); f4fma(ab[0], tv, f); }
            if (k >= 1)  { float4 tv = f4scale(gw[k - 1], f); f4add(av[1], tv); f4fma(ab[1], tv, f); }
        }
#pragma unroll
        for (int r = 0; r < 2; ++r) {
            float* dst = &vb2[(2 * rg + r) * 92 + colo * 2];
            *(float4*)&dst[0] = make_float4(av[r].x, ab[r].x, av[r].y, ab[r].y);
            *(float4*)&dst[4] = make_float4(av[r].z, ab[r].z, av[r].w, ab[r].w);
        }
    }
    __syncthreads();
    {
        const int erow = t >> 3, ecg = t & 7;
        const int oy = y0 + erow;
        const float* src = &vb2[erow * 92 + ecg * 8];
        float fl[28];
#pragma unroll
        for (int q = 0; q < 7; ++q) *(float4*)&fl[q * 4] = *(const float4*)(src + q * 4);
        float acc[2][4];
#pragma unroll
        for (int f = 0; f < 2; ++f)
#pragma unroll
            for (int j = 0; j < 4; ++j) acc[f][j] = 0.f;
#pragma unroll
        for (int m = 0; m < 14; ++m) {
#pragma unroll
            for (int j = 0; j < 4; ++j) {
                int kk = m - j;
                if (kk >= 0 && kk <= 10) {
                    acc[0][j] = fmaf(gw[kk], fl[m * 2 + 0], acc[0][j]);
                    acc[1][j] = fmaf(gw[kk], fl[m * 2 + 1], acc[1][j]);
                }
            }
        }
        if (oy < HPc) {
            size_t ob = (size_t)bi * HPWPc + (size_t)oy * HPc;
#pragma unroll
            for (int j = 0; j < 4; ++j) {
                int ox = x0 + ecg * 4 + j;
                if (ox < HPc) { muf[ob + ox] = acc[0][j]; ef2g[ob + ox] = acc[1][j]; }
            }
        }
    }
}

// K5: per (b, 32x32 tile): normalized xf tiles staged once in LDS, loop c over 64 channels.
// Vertical pass (rowgroup 2, 176 threads) reads x straight from global (L1/L2), writes the
// 5 blurred fields interleaved into vb5[row][col*5+f] (stride 228). Horizontal pass reads
// 18 ds_read_b128 per thread, evaluates SSIM, DPP-reduces, atomics into ssum[b,i,c].
__global__ __launch_bounds__(256, 3) void k5_main(const float* __restrict__ x, const float* __restrict__ xc,
                                                  const int* __restrict__ mask, const float* __restrict__ stats,
                                                  const float* __restrict__ muf, const float* __restrict__ ef2g,
                                                  float* __restrict__ ssum) {
    __shared__ __align__(16) float f0in[42 * 44];
    __shared__ __align__(16) float f1in[42 * 44];
    __shared__ __align__(16) float f2in[42 * 44];
    __shared__ __align__(16) float vb5[32 * 228];
    const int t = threadIdx.x;
    const int b = blockIdx.z;
    const int y0 = blockIdx.y * 32, x0 = blockIdx.x * 32;
    float gw[11]; gauss11(gw);
    // per-(b,i) normalization constants
    const float nst = stats[b * 8 + 0];
    float mean[3], rstd[3];
#pragma unroll
    for (int i = 0; i < 3; ++i) {
        float s1 = stats[b * 8 + 1 + i], s2 = stats[b * 8 + 4 + i];
        mean[i] = s1 / nst;
        rstd[i] = rsqrtf((s2 - s1 * s1 / nst) / (nst - 1.0f));
    }
    // stage normalized xf tiles (once per block)
    for (int q = t; q < 42 * 11; q += 256) {
        int row = q / 11, cg = q % 11;
        int gr = min(y0 + row, 255), gc = min(x0 + cg * 4, 252);
        int go = gr * 256 + gc;
        int lo = row * 44 + cg * 4;
        int4 mv = *(const int4*)(mask + (size_t)b * HWc + go);
        float m0 = (float)mv.x, m1 = (float)mv.y, m2 = (float)mv.z, m3 = (float)mv.w;
#pragma unroll
        for (int i = 0; i < 3; ++i) {
            float4 v = *(const float4*)(xc + (size_t)(b * 3 + i) * HWc + go);
            v.x = (v.x - mean[i]) * rstd[i] * m0;
            v.y = (v.y - mean[i]) * rstd[i] * m1;
            v.z = (v.z - mean[i]) * rstd[i] * m2;
            v.w = (v.w - mean[i]) * rstd[i] * m3;
            float* dst = (i == 0) ? f0in : (i == 1) ? f1in : f2in;
            *(float4*)&dst[lo] = v;
        }
    }
    // per-thread c-independent eval constants
    const int erow = t >> 3, ecg = t & 7;
    const int oy = y0 + erow;
    float Am[3][4], A2C1[3][4], S1C2[3][4], validf[4];
#pragma unroll
    for (int j = 0; j < 4; ++j) {
        int ox = x0 + ecg * 4 + j;
        bool vld = (oy < HPc) && (ox < HPc);
        validf[j] = vld ? 1.0f : 0.0f;
#pragma unroll
        for (int i = 0; i < 3; ++i) {
            float mu1 = 0.f, e2 = 0.f;
            if (vld) {
                size_t o = (size_t)(b * 3 + i) * HPWPc + (size_t)oy * HPc + ox;
                mu1 = muf[o]; e2 = ef2g[o];
            }
            Am[i][j] = mu1;
            A2C1[i][j] = fmaf(mu1, mu1, C1v);
            S1C2[i][j] = (e2 - mu1 * mu1) + C2v;
        }
    }
    __syncthreads();
    const float* xb = x + (size_t)b * Cn * HWc;
    const int vrg = t / 11, vcg = t % 11, vcolo = vcg * 4;
    const int gcb = min(x0 + vcolo, 252);
    const bool vact = (t < 176);
    for (int c = 0; c < Cn; ++c) {
        // ---- vertical pass: 176 threads, 2 output rows x 4 cols x 5 fields ----
        if (vact) {
            const float* xp = xb + (size_t)c * HWc;
            float4 a[2][5];
#pragma unroll
            for (int r = 0; r < 2; ++r)
#pragma unroll
                for (int f = 0; f < 5; ++f) a[r][f] = f4z();
#pragma unroll
            for (int k = 0; k < 12; ++k) {
                int gr = min(y0 + 2 * vrg + k, 255);
                float4 xv = *(const float4*)(xp + gr * 256 + gcb);
                int ro = (2 * vrg + k) * 44 + vcolo;
                float4 f0 = *(const float4*)&f0in[ro];
                float4 f1 = *(const float4*)&f1in[ro];
                float4 f2 = *(const float4*)&f2in[ro];
                if (k <= 10) {
                    float4 tv = f4scale(gw[k], xv);
                    f4add(a[0][0], tv); f4fma(a[0][1], tv, xv);
                    f4fma(a[0][2], tv, f0); f4fma(a[0][3], tv, f1); f4fma(a[0][4], tv, f2);
                }
                if (k >= 1) {
                    float4 tv = f4scale(gw[k - 1], xv);
                    f4add(a[1][0], tv); f4fma(a[1][1], tv, xv);
                    f4fma(a[1][2], tv, f0); f4fma(a[1][3], tv, f1); f4fma(a[1][4], tv, f2);
                }
            }
#pragma unroll
            for (int r = 0; r < 2; ++r) {
                float4 A = a[r][0], Bq = a[r][1], P0 = a[r][2], P1 = a[r][3], P2 = a[r][4];
                float* dst = &vb5[(2 * vrg + r) * 228 + vcolo * 5];
                *(float4*)&dst[0]  = make_float4(A.x, Bq.x, P0.x, P1.x);
                *(float4*)&dst[4]  = make_float4(P2.x, A.y, Bq.y, P0.y);
                *(float4*)&dst[8]  = make_float4(P1.y, P2.y, A.z, Bq.z);
                *(float4*)&dst[12] = make_float4(P0.z, P1.z, P2.z, A.w);
                *(float4*)&dst[16] = make_float4(Bq.w, P0.w, P1.w, P2.w);
            }
        }
        __syncthreads();
        // ---- horizontal pass + ssim eval + per-c reduction ----
        {
            const float* src = &vb5[erow * 228 + ecg * 20];
            float fl[72];
#pragma unroll
            for (int q = 0; q < 18; ++q) *(float4*)&fl[q * 4] = *(const float4*)(src + q * 4);
            float hacc[5][4];
#pragma unroll
            for (int f = 0; f < 5; ++f)
#pragma unroll
                for (int j = 0; j < 4; ++j) hacc[f][j] = 0.f;
#pragma unroll
            for (int m = 0; m < 14; ++m) {
#pragma unroll
                for (int j = 0; j < 4; ++j) {
                    int kk = m - j;
                    if (kk >= 0 && kk <= 10) {
#pragma unroll
                        for (int f = 0; f < 5; ++f) hacc[f][j] = fmaf(gw[kk], fl[m * 5 + f], hacc[f][j]);
                    }
                }
            }
            float sa0 = 0.f, sa1 = 0.f, sa2 = 0.f;
#pragma unroll
            for (int j = 0; j < 4; ++j) {
                float m2 = hacc[0][j];
                float m2sq = m2 * m2;
                float s2 = hacc[1][j] - m2sq;
                {
                    float am = Am[0][j] * m2;
                    float num = fmaf(2.f, am, C1v) * fmaf(2.f, hacc[2][j] - am, C2v);
                    float den = (A2C1[0][j] + m2sq) * (S1C2[0][j] + s2);
                    sa0 += validf[j] * num * __builtin_amdgcn_rcpf(den);
                }
                {
                    float am = Am[1][j] * m2;
                    float num = fmaf(2.f, am, C1v) * fmaf(2.f, hacc[3][j] - am, C2v);
                    float den = (A2C1[1][j] + m2sq) * (S1C2[1][j] + s2);
                    sa1 += validf[j] * num * __builtin_amdgcn_rcpf(den);
                }
                {
                    float am = Am[2][j] * m2;
                    float num = fmaf(2.f, am, C1v) * fmaf(2.f, hacc[4][j] - am, C2v);
                    float den = (A2C1[2][j] + m2sq) * (S1C2[2][j] + s2);
                    sa2 += validf[j] * num * __builtin_amdgcn_rcpf(den);
                }
            }
            sa0 = wave_sum64(sa0);
            sa1 = wave_sum64(sa1);
            sa2 = wave_sum64(sa2);
            if ((t & 63) == 63) {
                atomicAdd(&ssum[(b * 3 + 0) * 64 + c], sa0);
                atomicAdd(&ssum[(b * 3 + 1) * 64 + c], sa1);
                atomicAdd(&ssum[(b * 3 + 2) * 64 + c], sa2);
            }
        }
        __syncthreads();   // vb5 consumed before next vertical overwrites
    }
}

// K6: normalize ssim sums -> ssim_info output; conv3 over C + MLP head -> h output
__global__ __launch_bounds__(512) void k6_head(const float* __restrict__ ssum, const float* __restrict__ cw,
                                               const float* __restrict__ w1, const float* __restrict__ b1,
                                               const float* __restrict__ w2, const float* __restrict__ b2,
                                               float* __restrict__ out) {
    __shared__ float si[1536];
    __shared__ float h0[512];
    __shared__ float h1[512];
    const int t = threadIdx.x;
    const float inv = 1.0f / (float)HPWPc;
    for (int idx = t; idx < 1536; idx += 512) {
        float v = ssum[idx] * inv;
        si[idx] = v;
        out[512 + idx] = v;
    }
    __syncthreads();
    const int b = t >> 6, y = t & 63;
    float acc = 0.f;
#pragma unroll
    for (int i = 0; i < 3; ++i) {
#pragma unroll
        for (int kh = 0; kh < 3; ++kh) {
            int yy = y + kh - 1;
            if (yy >= 0 && yy < 64) acc = fmaf(si[(b * 3 + i) * 64 + yy], cw[i * 3 + kh], acc);
        }
    }
    h0[t] = fmaxf(acc, 0.f);
    __syncthreads();
    float a1 = b1[y];
    for (int c = 0; c < 64; ++c) a1 = fmaf(h0[(b << 6) + c], w1[(y << 6) + c], a1);
    h1[t] = fmaxf(a1, 0.f);
    __syncthreads();
    float a2 = b2[y];
    for (int c = 0; c < 64; ++c) a2 = fmaf(h1[(b << 6) + c], w2[(y << 6) + c], a2);
    out[t] = 1.f / (1.f + expf(-a2));
}

extern "C" void kernel_launch(void* const* d_in, const int* in_sizes, int n_in,
                              void* d_out, int out_size, void* d_ws, size_t ws_size,
                              hipStream_t stream) {
    const float* x      = (const float*)d_in[0];
    const int*   mask   = (const int*)d_in[1];
    const float* conv_w = (const float*)d_in[2];
    const float* w1     = (const float*)d_in[3];
    const float* b1     = (const float*)d_in[4];
    const float* w2     = (const float*)d_in[5];
    const float* b2     = (const float*)d_in[6];
    float* out = (float*)d_out;

    float* wsf   = (float*)d_ws;
    float* stats = wsf;                       // 64 floats (8 b x 8 slots)
    float* ssum  = wsf + 64;                  // 1536 floats
    float* xcf   = wsf + 1600;                // 8*3*65536 raw xc (max/mean/min)
    float* muf   = xcf + (size_t)Bn * 3 * HWc;      // 8*3*60516
    float* ef2   = muf + (size_t)Bn * 3 * HPWPc;    // 8*3*60516

    hipMemsetAsync(d_ws, 0, 6400, stream);  // stats + ssum accumulators

    k1_stats<<<dim3(64, 8), 256, 0, stream>>>(x, mask, xcf, stats);
    k4_blur3<<<dim3(8, 8, 24), 256, 0, stream>>>(xcf, mask, stats, muf, ef2);
    k5_main<<<dim3(8, 8, 8), 256, 0, stream>>>(x, xcf, mask, stats, muf, ef2, ssum);
    k6_head<<<1, 512, 0, stream>>>(ssum, conv_w, w1, b1, w2, b2, out);
}

// Round 3
// 1960.022 us; speedup vs baseline: 1.0105x; 1.0105x over previous
//
#include <hip/hip_runtime.h>
#include <cmath>

#define Bn   8
#define Cn   64
#define HWc  65536      // 256*256
#define HPc  246        // 256-11+1
#define HPWPc 60516     // 246*246
#define C1v  0.01f      // (0.01*10)^2
#define C2v  0.09f      // (0.03*10)^2

// 11-tap normalized gaussian, sigma=1.5 (double, then f32 cast — matches numpy)
static __device__ __forceinline__ void gauss11(float* gw) {
    double gg[11]; double s = 0.0;
#pragma unroll
    for (int j = 0; j < 11; ++j) { double d = (double)(j - 5); gg[j] = exp(-(d * d) / 4.5); s += gg[j]; }
#pragma unroll
    for (int j = 0; j < 11; ++j) gw[j] = (float)(gg[j] / s);
}

static __device__ __forceinline__ float4 f4z() { return make_float4(0.f, 0.f, 0.f, 0.f); }
static __device__ __forceinline__ float4 f4scale(float g, const float4 v) {
    return make_float4(g * v.x, g * v.y, g * v.z, g * v.w);
}
static __device__ __forceinline__ void f4add(float4& a, const float4 v) {
    a.x += v.x; a.y += v.y; a.z += v.z; a.w += v.w;
}
static __device__ __forceinline__ void f4fma(float4& a, const float4 u, const float4 v) {
    a.x = fmaf(u.x, v.x, a.x); a.y = fmaf(u.y, v.y, a.y);
    a.z = fmaf(u.z, v.z, a.z); a.w = fmaf(u.w, v.w, a.w);
}

// wave64 sum via DPP (VALU pipe, no LDS traffic). Result valid in lane 63.
static __device__ __forceinline__ float wave_sum64(float v) {
    v += __int_as_float(__builtin_amdgcn_update_dpp(0, __float_as_int(v), 0x111, 0xf, 0xf, true)); // row_shr:1
    v += __int_as_float(__builtin_amdgcn_update_dpp(0, __float_as_int(v), 0x112, 0xf, 0xf, true)); // row_shr:2
    v += __int_as_float(__builtin_amdgcn_update_dpp(0, __float_as_int(v), 0x114, 0xf, 0xf, true)); // row_shr:4
    v += __int_as_float(__builtin_amdgcn_update_dpp(0, __float_as_int(v), 0x118, 0xf, 0xf, true)); // row_shr:8
    v += __int_as_float(__builtin_amdgcn_update_dpp(0, __float_as_int(v), 0x142, 0xf, 0xf, true)); // row_bcast:15
    v += __int_as_float(__builtin_amdgcn_update_dpp(0, __float_as_int(v), 0x143, 0xf, 0xf, true)); // row_bcast:31
    return v;
}

// K1: channel max/mean/min (-> xcf planes, RAW) + masked stats atomics
__global__ __launch_bounds__(256) void k1_stats(const float* __restrict__ x, const int* __restrict__ mask,
                                                float* __restrict__ xcf, float* __restrict__ stats) {
    const int b = blockIdx.y;
    const int p0 = blockIdx.x * 1024 + threadIdx.x * 4;
    const float4* xp = (const float4*)(x + (size_t)b * Cn * HWc) + (p0 >> 2);
    float4 v = xp[0];
    float4 vmax = v, vmin = v, vsum = v;
#pragma unroll 4
    for (int c = 1; c < Cn; ++c) {
        float4 u = xp[(size_t)c * (HWc / 4)];
        vmax.x = fmaxf(vmax.x, u.x); vmax.y = fmaxf(vmax.y, u.y);
        vmax.z = fmaxf(vmax.z, u.z); vmax.w = fmaxf(vmax.w, u.w);
        vmin.x = fminf(vmin.x, u.x); vmin.y = fminf(vmin.y, u.y);
        vmin.z = fminf(vmin.z, u.z); vmin.w = fminf(vmin.w, u.w);
        vsum.x += u.x; vsum.y += u.y; vsum.z += u.z; vsum.w += u.w;
    }
    float4 vmean = make_float4(vsum.x * (1.f / 64.f), vsum.y * (1.f / 64.f),
                               vsum.z * (1.f / 64.f), vsum.w * (1.f / 64.f));
    *(float4*)(xcf + (size_t)(b * 3 + 0) * HWc + p0) = vmax;
    *(float4*)(xcf + (size_t)(b * 3 + 1) * HWc + p0) = vmean;
    *(float4*)(xcf + (size_t)(b * 3 + 2) * HWc + p0) = vmin;
    int4 mv = *(const int4*)(mask + (size_t)b * HWc + p0);
    float m0 = (float)mv.x, m1 = (float)mv.y, m2 = (float)mv.z, m3 = (float)mv.w;
    float r[7];
    r[0] = m0 + m1 + m2 + m3;
    r[1] = vmax.x * m0 + vmax.y * m1 + vmax.z * m2 + vmax.w * m3;
    r[2] = vmean.x * m0 + vmean.y * m1 + vmean.z * m2 + vmean.w * m3;
    r[3] = vmin.x * m0 + vmin.y * m1 + vmin.z * m2 + vmin.w * m3;
    r[4] = vmax.x * vmax.x * m0 + vmax.y * vmax.y * m1 + vmax.z * vmax.z * m2 + vmax.w * vmax.w * m3;
    r[5] = vmean.x * vmean.x * m0 + vmean.y * vmean.y * m1 + vmean.z * vmean.z * m2 + vmean.w * vmean.w * m3;
    r[6] = vmin.x * vmin.x * m0 + vmin.y * vmin.y * m1 + vmin.z * vmin.z * m2 + vmin.w * vmin.w * m3;
#pragma unroll
    for (int k = 0; k < 7; ++k) {
        float vv = wave_sum64(r[k]);
        if ((threadIdx.x & 63) == 63) atomicAdd(&stats[b * 8 + k], vv);
    }
}

// K4: mu_f = blur(xf), ef2 = blur(xf^2); xf computed inline from raw xc + mask + stats.
// Vertical pass from global (rowgroup 2, 176 threads), interleaved vb2; horizontal pass
// is a rolling b128 accumulate (NO local-array address-taking -> no scratch spill).
__global__ __launch_bounds__(256) void k4_blur3(const float* __restrict__ xc, const int* __restrict__ mask,
                                                const float* __restrict__ stats,
                                                float* __restrict__ muf, float* __restrict__ ef2g) {
    __shared__ __align__(16) float vb2[32 * 92];
    const int t = threadIdx.x;
    const int bi = blockIdx.z, b = bi / 3, i = bi % 3;
    const int y0 = blockIdx.y * 32, x0 = blockIdx.x * 32;
    float gw[11]; gauss11(gw);
    const float nst = stats[b * 8 + 0];
    const float s1 = stats[b * 8 + 1 + i], s2 = stats[b * 8 + 4 + i];
    const float mean = s1 / nst;
    const float rstd = rsqrtf((s2 - s1 * s1 / nst) / (nst - 1.0f));
    if (t < 176) {
        const int rg = t / 11, cg = t % 11, colo = cg * 4;
        const int gcb = min(x0 + colo, 252);
        const float* xp = xc + (size_t)bi * HWc;
        const int* mp = mask + (size_t)b * HWc;
        float4 av[2], ab[2];
#pragma unroll
        for (int r = 0; r < 2; ++r) { av[r] = f4z(); ab[r] = f4z(); }
#pragma unroll
        for (int k = 0; k < 12; ++k) {
            int gr = min(y0 + 2 * rg + k, 255);
            float4 v = *(const float4*)(xp + gr * 256 + gcb);
            int4 mv = *(const int4*)(mp + gr * 256 + gcb);
            float4 f;
            f.x = (v.x - mean) * rstd * (float)mv.x;
            f.y = (v.y - mean) * rstd * (float)mv.y;
            f.z = (v.z - mean) * rstd * (float)mv.z;
            f.w = (v.w - mean) * rstd * (float)mv.w;
            if (k <= 10) { float4 tv = f4scale(gw[k], f); f4add(av[0], tv); f4fma(ab[0], tv, f); }
            if (k >= 1)  { float4 tv = f4scale(gw[k - 1], f); f4add(av[1], tv); f4fma(ab[1], tv, f); }
        }
#pragma unroll
        for (int r = 0; r < 2; ++r) {
            float* dst = &vb2[(2 * rg + r) * 92 + colo * 2];
            *(float4*)&dst[0] = make_float4(av[r].x, ab[r].x, av[r].y, ab[r].y);
            *(float4*)&dst[4] = make_float4(av[r].z, ab[r].z, av[r].w, ab[r].w);
        }
    }
    __syncthreads();
    {
        const int erow = t >> 3, ecg = t & 7;
        const int oy = y0 + erow;
        const float* src = &vb2[erow * 92 + ecg * 8];
        float acc[2][4];
#pragma unroll
        for (int f = 0; f < 2; ++f)
#pragma unroll
            for (int j = 0; j < 4; ++j) acc[f][j] = 0.f;
#pragma unroll
        for (int q = 0; q < 7; ++q) {
            float4 v4 = *(const float4*)(src + q * 4);
            float vv[4] = {v4.x, v4.y, v4.z, v4.w};
#pragma unroll
            for (int e = 0; e < 4; ++e) {
                const int idx = q * 4 + e;
                const int m = idx >> 1, f = idx & 1;
#pragma unroll
                for (int j = 0; j < 4; ++j) {
                    const int kk = m - j;
                    if (kk >= 0 && kk <= 10) acc[f][j] = fmaf(gw[kk], vv[e], acc[f][j]);
                }
            }
        }
        if (oy < HPc) {
            size_t ob = (size_t)bi * HPWPc + (size_t)oy * HPc;
#pragma unroll
            for (int j = 0; j < 4; ++j) {
                int ox = x0 + ecg * 4 + j;
                if (ox < HPc) { muf[ob + ox] = acc[0][j]; ef2g[ob + ox] = acc[1][j]; }
            }
        }
    }
}

// K5: per (b, 32x32 tile): normalized xf tiles staged once in LDS, loop c over 64 channels.
// Vertical pass (176 threads, rowgroup 2) reads x from global (L1/L2-served), writes 5
// blurred fields interleaved into vb5[row][col*5+f]. Horizontal pass: rolling b128
// accumulate straight into hacc[5][4] (no local-array spill), SSIM eval, DPP reduce.
__global__ __launch_bounds__(256, 3) void k5_main(const float* __restrict__ x, const float* __restrict__ xc,
                                                  const int* __restrict__ mask, const float* __restrict__ stats,
                                                  const float* __restrict__ muf, const float* __restrict__ ef2g,
                                                  float* __restrict__ ssum) {
    __shared__ __align__(16) float f0in[42 * 44];
    __shared__ __align__(16) float f1in[42 * 44];
    __shared__ __align__(16) float f2in[42 * 44];
    __shared__ __align__(16) float vb5[32 * 228];
    const int t = threadIdx.x;
    const int b = blockIdx.z;
    const int y0 = blockIdx.y * 32, x0 = blockIdx.x * 32;
    float gw[11]; gauss11(gw);
    const float nst = stats[b * 8 + 0];
    float mean[3], rstd[3];
#pragma unroll
    for (int i = 0; i < 3; ++i) {
        float s1 = stats[b * 8 + 1 + i], s2 = stats[b * 8 + 4 + i];
        mean[i] = s1 / nst;
        rstd[i] = rsqrtf((s2 - s1 * s1 / nst) / (nst - 1.0f));
    }
    // stage normalized xf tiles (once per block)
    for (int q = t; q < 42 * 11; q += 256) {
        int row = q / 11, cg = q % 11;
        int gr = min(y0 + row, 255), gc = min(x0 + cg * 4, 252);
        int go = gr * 256 + gc;
        int lo = row * 44 + cg * 4;
        int4 mv = *(const int4*)(mask + (size_t)b * HWc + go);
        float m0 = (float)mv.x, m1 = (float)mv.y, m2 = (float)mv.z, m3 = (float)mv.w;
#pragma unroll
        for (int i = 0; i < 3; ++i) {
            float4 v = *(const float4*)(xc + (size_t)(b * 3 + i) * HWc + go);
            v.x = (v.x - mean[i]) * rstd[i] * m0;
            v.y = (v.y - mean[i]) * rstd[i] * m1;
            v.z = (v.z - mean[i]) * rstd[i] * m2;
            v.w = (v.w - mean[i]) * rstd[i] * m3;
            float* dst = (i == 0) ? f0in : (i == 1) ? f1in : f2in;
            *(float4*)&dst[lo] = v;
        }
    }
    // per-thread c-independent eval constants
    const int erow = t >> 3, ecg = t & 7;
    const int oy = y0 + erow;
    float Am[3][4], A2C1[3][4], S1C2[3][4], validf[4];
#pragma unroll
    for (int j = 0; j < 4; ++j) {
        int ox = x0 + ecg * 4 + j;
        bool vld = (oy < HPc) && (ox < HPc);
        validf[j] = vld ? 1.0f : 0.0f;
#pragma unroll
        for (int i = 0; i < 3; ++i) {
            float mu1 = 0.f, e2 = 0.f;
            if (vld) {
                size_t o = (size_t)(b * 3 + i) * HPWPc + (size_t)oy * HPc + ox;
                mu1 = muf[o]; e2 = ef2g[o];
            }
            Am[i][j] = mu1;
            A2C1[i][j] = fmaf(mu1, mu1, C1v);
            S1C2[i][j] = (e2 - mu1 * mu1) + C2v;
        }
    }
    __syncthreads();
    const float* xb = x + (size_t)b * Cn * HWc;
    const int vrg = t / 11, vcg = t % 11, vcolo = vcg * 4;
    const int gcb = min(x0 + vcolo, 252);
    const bool vact = (t < 176);
    for (int c = 0; c < Cn; ++c) {
        // ---- vertical pass: 176 threads, 2 output rows x 4 cols x 5 fields ----
        if (vact) {
            const float* xp = xb + (size_t)c * HWc;
            float4 a[2][5];
#pragma unroll
            for (int r = 0; r < 2; ++r)
#pragma unroll
                for (int f = 0; f < 5; ++f) a[r][f] = f4z();
#pragma unroll
            for (int k = 0; k < 12; ++k) {
                int gr = min(y0 + 2 * vrg + k, 255);
                float4 xv = *(const float4*)(xp + gr * 256 + gcb);
                int ro = (2 * vrg + k) * 44 + vcolo;
                float4 f0 = *(const float4*)&f0in[ro];
                float4 f1 = *(const float4*)&f1in[ro];
                float4 f2 = *(const float4*)&f2in[ro];
                if (k <= 10) {
                    float4 tv = f4scale(gw[k], xv);
                    f4add(a[0][0], tv); f4fma(a[0][1], tv, xv);
                    f4fma(a[0][2], tv, f0); f4fma(a[0][3], tv, f1); f4fma(a[0][4], tv, f2);
                }
                if (k >= 1) {
                    float4 tv = f4scale(gw[k - 1], xv);
                    f4add(a[1][0], tv); f4fma(a[1][1], tv, xv);
                    f4fma(a[1][2], tv, f0); f4fma(a[1][3], tv, f1); f4fma(a[1][4], tv, f2);
                }
            }
#pragma unroll
            for (int r = 0; r < 2; ++r) {
                float4 A = a[r][0], Bq = a[r][1], P0 = a[r][2], P1 = a[r][3], P2 = a[r][4];
                float* dst = &vb5[(2 * vrg + r) * 228 + vcolo * 5];
                *(float4*)&dst[0]  = make_float4(A.x, Bq.x, P0.x, P1.x);
                *(float4*)&dst[4]  = make_float4(P2.x, A.y, Bq.y, P0.y);
                *(float4*)&dst[8]  = make_float4(P1.y, P2.y, A.z, Bq.z);
                *(float4*)&dst[12] = make_float4(P0.z, P1.z, P2.z, A.w);
                *(float4*)&dst[16] = make_float4(Bq.w, P0.w, P1.w, P2.w);
            }
        }
        __syncthreads();
        // ---- horizontal pass: rolling b128 accumulate + ssim eval + per-c reduction ----
        {
            const float* src = &vb5[erow * 228 + ecg * 20];
            float hacc[5][4];
#pragma unroll
            for (int f = 0; f < 5; ++f)
#pragma unroll
                for (int j = 0; j < 4; ++j) hacc[f][j] = 0.f;
#pragma unroll
            for (int q = 0; q < 18; ++q) {
                float4 v4 = *(const float4*)(src + q * 4);
                float vv[4] = {v4.x, v4.y, v4.z, v4.w};
#pragma unroll
                for (int e = 0; e < 4; ++e) {
                    const int idx = q * 4 + e;
                    if (idx < 70) {
                        const int m = idx / 5, f = idx % 5;
#pragma unroll
                        for (int j = 0; j < 4; ++j) {
                            const int kk = m - j;
                            if (kk >= 0 && kk <= 10) hacc[f][j] = fmaf(gw[kk], vv[e], hacc[f][j]);
                        }
                    }
                }
            }
            float sa0 = 0.f, sa1 = 0.f, sa2 = 0.f;
#pragma unroll
            for (int j = 0; j < 4; ++j) {
                float m2 = hacc[0][j];
                float m2sq = m2 * m2;
                float s2 = hacc[1][j] - m2sq;
                {
                    float am = Am[0][j] * m2;
                    float num = fmaf(2.f, am, C1v) * fmaf(2.f, hacc[2][j] - am, C2v);
                    float den = (A2C1[0][j] + m2sq) * (S1C2[0][j] + s2);
                    sa0 += validf[j] * num * __builtin_amdgcn_rcpf(den);
                }
                {
                    float am = Am[1][j] * m2;
                    float num = fmaf(2.f, am, C1v) * fmaf(2.f, hacc[3][j] - am, C2v);
                    float den = (A2C1[1][j] + m2sq) * (S1C2[1][j] + s2);
                    sa1 += validf[j] * num * __builtin_amdgcn_rcpf(den);
                }
                {
                    float am = Am[2][j] * m2;
                    float num = fmaf(2.f, am, C1v) * fmaf(2.f, hacc[4][j] - am, C2v);
                    float den = (A2C1[2][j] + m2sq) * (S1C2[2][j] + s2);
                    sa2 += validf[j] * num * __builtin_amdgcn_rcpf(den);
                }
            }
            sa0 = wave_sum64(sa0);
            sa1 = wave_sum64(sa1);
            sa2 = wave_sum64(sa2);
            if ((t & 63) == 63) {
                atomicAdd(&ssum[(b * 3 + 0) * 64 + c], sa0);
                atomicAdd(&ssum[(b * 3 + 1) * 64 + c], sa1);
                atomicAdd(&ssum[(b * 3 + 2) * 64 + c], sa2);
            }
        }
        __syncthreads();   // vb5 consumed before next vertical overwrites
    }
}

// K6: normalize ssim sums -> ssim_info output; conv3 over C + MLP head -> h output
__global__ __launch_bounds__(512) void k6_head(const float* __restrict__ ssum, const float* __restrict__ cw,
                                               const float* __restrict__ w1, const float* __restrict__ b1,
                                               const float* __restrict__ w2, const float* __restrict__ b2,
                                               float* __restrict__ out) {
    __shared__ float si[1536];
    __shared__ float h0[512];
    __shared__ float h1[512];
    const int t = threadIdx.x;
    const float inv = 1.0f / (float)HPWPc;
    for (int idx = t; idx < 1536; idx += 512) {
        float v = ssum[idx] * inv;
        si[idx] = v;
        out[512 + idx] = v;
    }
    __syncthreads();
    const int b = t >> 6, y = t & 63;
    float acc = 0.f;
#pragma unroll
    for (int i = 0; i < 3; ++i) {
#pragma unroll
        for (int kh = 0; kh < 3; ++kh) {
            int yy = y + kh - 1;
            if (yy >= 0 && yy < 64) acc = fmaf(si[(b * 3 + i) * 64 + yy], cw[i * 3 + kh], acc);
        }
    }
    h0[t] = fmaxf(acc, 0.f);
    __syncthreads();
    float a1 = b1[y];
    for (int c = 0; c < 64; ++c) a1 = fmaf(h0[(b << 6) + c], w1[(y << 6) + c], a1);
    h1[t] = fmaxf(a1, 0.f);
    __syncthreads();
    float a2 = b2[y];
    for (int c = 0; c < 64; ++c) a2 = fmaf(h1[(b << 6) + c], w2[(y << 6) + c], a2);
    out[t] = 1.f / (1.f + expf(-a2));
}

extern "C" void kernel_launch(void* const* d_in, const int* in_sizes, int n_in,
                              void* d_out, int out_size, void* d_ws, size_t ws_size,
                              hipStream_t stream) {
    const float* x      = (const float*)d_in[0];
    const int*   mask   = (const int*)d_in[1];
    const float* conv_w = (const float*)d_in[2];
    const float* w1     = (const float*)d_in[3];
    const float* b1     = (const float*)d_in[4];
    const float* w2     = (const float*)d_in[5];
    const float* b2     = (const float*)d_in[6];
    float* out = (float*)d_out;

    float* wsf   = (float*)d_ws;
    float* stats = wsf;                       // 64 floats (8 b x 8 slots)
    float* ssum  = wsf + 64;                  // 1536 floats
    float* xcf   = wsf + 1600;                // 8*3*65536 raw xc (max/mean/min)
    float* muf   = xcf + (size_t)Bn * 3 * HWc;      // 8*3*60516
    float* ef2   = muf + (size_t)Bn * 3 * HPWPc;    // 8*3*60516

    hipMemsetAsync(d_ws, 0, 6400, stream);  // stats + ssum accumulators

    k1_stats<<<dim3(64, 8), 256, 0, stream>>>(x, mask, xcf, stats);
    k4_blur3<<<dim3(8, 8, 24), 256, 0, stream>>>(xcf, mask, stats, muf, ef2);
    k5_main<<<dim3(8, 8, 8), 256, 0, stream>>>(x, xcf, mask, stats, muf, ef2, ssum);
    k6_head<<<1, 512, 0, stream>>>(ssum, conv_w, w1, b1, w2, b2, out);
}

// Round 4
// 1837.689 us; speedup vs baseline: 1.0777x; 1.0666x over previous
//
#include <hip/hip_runtime.h>
#include <cmath>

#define Bn   8
#define Cn   64
#define HWc  65536      // 256*256
#define HPc  246        // 256-11+1
#define HPWPc 60516     // 246*246
#define C1v  0.01f      // (0.01*10)^2
#define C2v  0.09f      // (0.03*10)^2

// 11-tap normalized gaussian, sigma=1.5 (double, then f32 cast — matches numpy)
static __device__ __forceinline__ void gauss11(float* gw) {
    double gg[11]; double s = 0.0;
#pragma unroll
    for (int j = 0; j < 11; ++j) { double d = (double)(j - 5); gg[j] = exp(-(d * d) / 4.5); s += gg[j]; }
#pragma unroll
    for (int j = 0; j < 11; ++j) gw[j] = (float)(gg[j] / s);
}

static __device__ __forceinline__ float4 f4z() { return make_float4(0.f, 0.f, 0.f, 0.f); }
static __device__ __forceinline__ float4 f4scale(float g, const float4 v) {
    return make_float4(g * v.x, g * v.y, g * v.z, g * v.w);
}
static __device__ __forceinline__ void f4add(float4& a, const float4 v) {
    a.x += v.x; a.y += v.y; a.z += v.z; a.w += v.w;
}
static __device__ __forceinline__ void f4fma(float4& a, const float4 u, const float4 v) {
    a.x = fmaf(u.x, v.x, a.x); a.y = fmaf(u.y, v.y, a.y);
    a.z = fmaf(u.z, v.z, a.z); a.w = fmaf(u.w, v.w, a.w);
}

// wave64 sum via DPP (VALU pipe, no LDS traffic). Result valid in lane 63.
static __device__ __forceinline__ float wave_sum64(float v) {
    v += __int_as_float(__builtin_amdgcn_update_dpp(0, __float_as_int(v), 0x111, 0xf, 0xf, true)); // row_shr:1
    v += __int_as_float(__builtin_amdgcn_update_dpp(0, __float_as_int(v), 0x112, 0xf, 0xf, true)); // row_shr:2
    v += __int_as_float(__builtin_amdgcn_update_dpp(0, __float_as_int(v), 0x114, 0xf, 0xf, true)); // row_shr:4
    v += __int_as_float(__builtin_amdgcn_update_dpp(0, __float_as_int(v), 0x118, 0xf, 0xf, true)); // row_shr:8
    v += __int_as_float(__builtin_amdgcn_update_dpp(0, __float_as_int(v), 0x142, 0xf, 0xf, true)); // row_bcast:15
    v += __int_as_float(__builtin_amdgcn_update_dpp(0, __float_as_int(v), 0x143, 0xf, 0xf, true)); // row_bcast:31
    return v;
}

// K1: channel max/mean/min (-> xcf planes, RAW) + masked stats atomics
__global__ __launch_bounds__(256) void k1_stats(const float* __restrict__ x, const int* __restrict__ mask,
                                                float* __restrict__ xcf, float* __restrict__ stats) {
    const int b = blockIdx.y;
    const int p0 = blockIdx.x * 1024 + threadIdx.x * 4;
    const float4* xp = (const float4*)(x + (size_t)b * Cn * HWc) + (p0 >> 2);
    float4 v = xp[0];
    float4 vmax = v, vmin = v, vsum = v;
#pragma unroll 4
    for (int c = 1; c < Cn; ++c) {
        float4 u = xp[(size_t)c * (HWc / 4)];
        vmax.x = fmaxf(vmax.x, u.x); vmax.y = fmaxf(vmax.y, u.y);
        vmax.z = fmaxf(vmax.z, u.z); vmax.w = fmaxf(vmax.w, u.w);
        vmin.x = fminf(vmin.x, u.x); vmin.y = fminf(vmin.y, u.y);
        vmin.z = fminf(vmin.z, u.z); vmin.w = fminf(vmin.w, u.w);
        vsum.x += u.x; vsum.y += u.y; vsum.z += u.z; vsum.w += u.w;
    }
    float4 vmean = make_float4(vsum.x * (1.f / 64.f), vsum.y * (1.f / 64.f),
                               vsum.z * (1.f / 64.f), vsum.w * (1.f / 64.f));
    *(float4*)(xcf + (size_t)(b * 3 + 0) * HWc + p0) = vmax;
    *(float4*)(xcf + (size_t)(b * 3 + 1) * HWc + p0) = vmean;
    *(float4*)(xcf + (size_t)(b * 3 + 2) * HWc + p0) = vmin;
    int4 mv = *(const int4*)(mask + (size_t)b * HWc + p0);
    float m0 = (float)mv.x, m1 = (float)mv.y, m2 = (float)mv.z, m3 = (float)mv.w;
    float r[7];
    r[0] = m0 + m1 + m2 + m3;
    r[1] = vmax.x * m0 + vmax.y * m1 + vmax.z * m2 + vmax.w * m3;
    r[2] = vmean.x * m0 + vmean.y * m1 + vmean.z * m2 + vmean.w * m3;
    r[3] = vmin.x * m0 + vmin.y * m1 + vmin.z * m2 + vmin.w * m3;
    r[4] = vmax.x * vmax.x * m0 + vmax.y * vmax.y * m1 + vmax.z * vmax.z * m2 + vmax.w * vmax.w * m3;
    r[5] = vmean.x * vmean.x * m0 + vmean.y * vmean.y * m1 + vmean.z * vmean.z * m2 + vmean.w * vmean.w * m3;
    r[6] = vmin.x * vmin.x * m0 + vmin.y * vmin.y * m1 + vmin.z * vmin.z * m2 + vmin.w * vmin.w * m3;
#pragma unroll
    for (int k = 0; k < 7; ++k) {
        float vv = wave_sum64(r[k]);
        if ((threadIdx.x & 63) == 63) atomicAdd(&stats[b * 8 + k], vv);
    }
}

// K4: mu_f = blur(xf), ef2 = blur(xf^2); xf computed inline from raw xc + mask + stats.
__global__ __launch_bounds__(256) void k4_blur3(const float* __restrict__ xc, const int* __restrict__ mask,
                                                const float* __restrict__ stats,
                                                float* __restrict__ muf, float* __restrict__ ef2g) {
    __shared__ __align__(16) float vb2[32 * 92];
    const int t = threadIdx.x;
    const int bi = blockIdx.z, b = bi / 3, i = bi % 3;
    const int y0 = blockIdx.y * 32, x0 = blockIdx.x * 32;
    float gw[11]; gauss11(gw);
    const float nst = stats[b * 8 + 0];
    const float s1 = stats[b * 8 + 1 + i], s2 = stats[b * 8 + 4 + i];
    const float mean = s1 / nst;
    const float rstd = rsqrtf((s2 - s1 * s1 / nst) / (nst - 1.0f));
    if (t < 176) {
        const int rg = t / 11, cg = t % 11, colo = cg * 4;
        const int gcb = min(x0 + colo, 252);
        const float* xp = xc + (size_t)bi * HWc;
        const int* mp = mask + (size_t)b * HWc;
        float4 av0 = f4z(), ab0 = f4z(), av1 = f4z(), ab1 = f4z();
#pragma unroll
        for (int k = 0; k < 12; ++k) {
            int gr = min(y0 + 2 * rg + k, 255);
            float4 v = *(const float4*)(xp + gr * 256 + gcb);
            int4 mv = *(const int4*)(mp + gr * 256 + gcb);
            float4 f;
            f.x = (v.x - mean) * rstd * (float)mv.x;
            f.y = (v.y - mean) * rstd * (float)mv.y;
            f.z = (v.z - mean) * rstd * (float)mv.z;
            f.w = (v.w - mean) * rstd * (float)mv.w;
            if (k <= 10) { float4 tv = f4scale(gw[k], f); f4add(av0, tv); f4fma(ab0, tv, f); }
            if (k >= 1)  { float4 tv = f4scale(gw[k - 1], f); f4add(av1, tv); f4fma(ab1, tv, f); }
        }
        {
            float* dst = &vb2[(2 * rg + 0) * 92 + colo * 2];
            *(float4*)&dst[0] = make_float4(av0.x, ab0.x, av0.y, ab0.y);
            *(float4*)&dst[4] = make_float4(av0.z, ab0.z, av0.w, ab0.w);
        }
        {
            float* dst = &vb2[(2 * rg + 1) * 92 + colo * 2];
            *(float4*)&dst[0] = make_float4(av1.x, ab1.x, av1.y, ab1.y);
            *(float4*)&dst[4] = make_float4(av1.z, ab1.z, av1.w, ab1.w);
        }
    }
    __syncthreads();
    {
        const int erow = t >> 3, ecg = t & 7;
        const int oy = y0 + erow;
        const float* src = &vb2[erow * 92 + ecg * 8];
        float a00 = 0.f, a01 = 0.f, a02 = 0.f, a03 = 0.f;
        float a10 = 0.f, a11 = 0.f, a12 = 0.f, a13 = 0.f;
#pragma unroll
        for (int m = 0; m < 14; ++m) {
            float v0 = src[m * 2 + 0];
            float v1 = src[m * 2 + 1];
#pragma unroll
            for (int j = 0; j < 4; ++j) {
                const int kk = m - j;
                if (kk >= 0 && kk <= 10) {
                    if (j == 0) { a00 = fmaf(gw[kk], v0, a00); a10 = fmaf(gw[kk], v1, a10); }
                    if (j == 1) { a01 = fmaf(gw[kk], v0, a01); a11 = fmaf(gw[kk], v1, a11); }
                    if (j == 2) { a02 = fmaf(gw[kk], v0, a02); a12 = fmaf(gw[kk], v1, a12); }
                    if (j == 3) { a03 = fmaf(gw[kk], v0, a03); a13 = fmaf(gw[kk], v1, a13); }
                }
            }
        }
        if (oy < HPc) {
            size_t ob = (size_t)bi * HPWPc + (size_t)oy * HPc;
            int oxb = x0 + ecg * 4;
            if (oxb + 0 < HPc) { muf[ob + oxb + 0] = a00; ef2g[ob + oxb + 0] = a10; }
            if (oxb + 1 < HPc) { muf[ob + oxb + 1] = a01; ef2g[ob + oxb + 1] = a11; }
            if (oxb + 2 < HPc) { muf[ob + oxb + 2] = a02; ef2g[ob + oxb + 2] = a12; }
            if (oxb + 3 < HPc) { muf[ob + oxb + 3] = a03; ef2g[ob + oxb + 3] = a13; }
        }
    }
}

// ---- K5 macro machinery (NO local arrays anywhere — spill-proof) ----
#define T(F,J,KK,V) h##F##_##J = fmaf(G##KK, (V), h##F##_##J);
#define TM0(F,V)  T(F,0,0,V)
#define TM1(F,V)  T(F,0,1,V) T(F,1,0,V)
#define TM2(F,V)  T(F,0,2,V) T(F,1,1,V) T(F,2,0,V)
#define TM3(F,V)  T(F,0,3,V) T(F,1,2,V) T(F,2,1,V) T(F,3,0,V)
#define TM4(F,V)  T(F,0,4,V) T(F,1,3,V) T(F,2,2,V) T(F,3,1,V)
#define TM5(F,V)  T(F,0,5,V) T(F,1,4,V) T(F,2,3,V) T(F,3,2,V)
#define TM6(F,V)  T(F,0,6,V) T(F,1,5,V) T(F,2,4,V) T(F,3,3,V)
#define TM7(F,V)  T(F,0,7,V) T(F,1,6,V) T(F,2,5,V) T(F,3,4,V)
#define TM8(F,V)  T(F,0,8,V) T(F,1,7,V) T(F,2,6,V) T(F,3,5,V)
#define TM9(F,V)  T(F,0,9,V) T(F,1,8,V) T(F,2,7,V) T(F,3,6,V)
#define TM10(F,V) T(F,0,10,V) T(F,1,9,V) T(F,2,8,V) T(F,3,7,V)
#define TM11(F,V) T(F,1,10,V) T(F,2,9,V) T(F,3,8,V)
#define TM12(F,V) T(F,2,10,V) T(F,3,9,V)
#define TM13(F,V) T(F,3,10,V)

#define DECLH(J) float h0_##J = 0.f, h1_##J = 0.f, h2_##J = 0.f, h3_##J = 0.f, h4_##J = 0.f;
#define DECLJ(J) float M0_##J, M1_##J, M2_##J, P0_##J, P1_##J, P2_##J, S0_##J, S1_##J, S2_##J, V##J;
#define SETI(I,J) { float mu1 = 0.f, e2 = 0.f; \
    if (vld) { size_t o = (size_t)(b * 3 + I) * HPWPc + (size_t)oy * HPc + ox; mu1 = muf[o]; e2 = ef2g[o]; } \
    M##I##_##J = mu1; P##I##_##J = fmaf(mu1, mu1, C1v); S##I##_##J = (e2 - mu1 * mu1) + C2v; }
#define SETJ(J) { int ox = ox0 + J; bool vld = (oy < HPc) && (ox < HPc); V##J = vld ? 1.f : 0.f; \
    SETI(0,J) SETI(1,J) SETI(2,J) }

#define SSIMJ(J) { \
    float m2 = h0_##J; float m2sq = m2 * m2; float s2 = h1_##J - m2sq; \
    { float am = M0_##J * m2; float num = fmaf(2.f, am, C1v) * fmaf(2.f, h2_##J - am, C2v); \
      float den = (P0_##J + m2sq) * (S0_##J + s2); sa0 += V##J * num * __builtin_amdgcn_rcpf(den); } \
    { float am = M1_##J * m2; float num = fmaf(2.f, am, C1v) * fmaf(2.f, h3_##J - am, C2v); \
      float den = (P1_##J + m2sq) * (S1_##J + s2); sa1 += V##J * num * __builtin_amdgcn_rcpf(den); } \
    { float am = M2_##J * m2; float num = fmaf(2.f, am, C1v) * fmaf(2.f, h4_##J - am, C2v); \
      float den = (P2_##J + m2sq) * (S2_##J + s2); sa2 += V##J * num * __builtin_amdgcn_rcpf(den); } }

#define VSTEP(K, DOA, DOB, GA, GB) { \
    int gr = y0 + 2 * vrg + (K); gr = (gr > 255) ? 255 : gr; \
    float4 xv = *(const float4*)(xp + gr * 256 + gcb); \
    const int ro = (2 * vrg + (K)) * 44 + vcolo; \
    float4 f0 = *(const float4*)&f0in[ro]; \
    float4 f1v = *(const float4*)&f1in[ro]; \
    float4 f2v = *(const float4*)&f2in[ro]; \
    if (DOA) { float4 tv = f4scale((GA), xv); f4add(xA0, tv); f4fma(xQ0, tv, xv); \
               f4fma(p00, tv, f0); f4fma(p10, tv, f1v); f4fma(p20, tv, f2v); } \
    if (DOB) { float4 tv = f4scale((GB), xv); f4add(xA1, tv); f4fma(xQ1, tv, xv); \
               f4fma(p01, tv, f0); f4fma(p11, tv, f1v); f4fma(p21, tv, f2v); } }

// K5: per (b, chunk, 32x32 tile): xf tiles staged in LDS once; c-chunk loop.
// Vertical (176 thr, rowgroup 2) reads x from global, accumulates 5 fields into named
// float4 regs, stores interleaved vb5[row][col*5+f] (stride 228). Horizontal: 18 named
// b128 loads -> 220 macro FMAs into 20 named scalars -> SSIM -> DPP reduce -> atomics.
__global__ __launch_bounds__(256, 3) void k5_main(const float* __restrict__ x, const float* __restrict__ xc,
                                                  const int* __restrict__ mask, const float* __restrict__ stats,
                                                  const float* __restrict__ muf, const float* __restrict__ ef2g,
                                                  float* __restrict__ ssum) {
    __shared__ __align__(16) float f0in[42 * 44];
    __shared__ __align__(16) float f1in[42 * 44];
    __shared__ __align__(16) float f2in[42 * 44];
    __shared__ __align__(16) float vb5[32 * 228];
    const int t = threadIdx.x;
    const int bz = blockIdx.z;
    const int b = bz / 3, ch = bz % 3;
    const int c0 = (ch == 0) ? 0 : (ch == 1) ? 22 : 43;
    const int c1 = (ch == 0) ? 22 : (ch == 1) ? 43 : 64;
    const int y0 = blockIdx.y * 32, x0 = blockIdx.x * 32;
    // gauss weights as named scalars (same numerics as gauss11)
    const double e0 = exp(-25.0 / 4.5), e1 = exp(-16.0 / 4.5), e2d = exp(-9.0 / 4.5),
                 e3 = exp(-4.0 / 4.5), e4 = exp(-1.0 / 4.5);
    const double sg = 1.0 + 2.0 * (e0 + e1 + e2d + e3 + e4);
    const float G0 = (float)(e0 / sg), G1 = (float)(e1 / sg), G2 = (float)(e2d / sg),
                G3 = (float)(e3 / sg), G4 = (float)(e4 / sg), G5 = (float)(1.0 / sg);
    const float G6 = G4, G7 = G3, G8 = G2, G9 = G1, G10 = G0;
    // per-(b,i) normalization constants
    const float nst = stats[b * 8 + 0];
    const float s1a = stats[b * 8 + 1], s2a = stats[b * 8 + 4];
    const float s1b = stats[b * 8 + 2], s2b = stats[b * 8 + 5];
    const float s1c = stats[b * 8 + 3], s2c = stats[b * 8 + 6];
    const float mean0 = s1a / nst, rstd0 = rsqrtf((s2a - s1a * s1a / nst) / (nst - 1.0f));
    const float mean1 = s1b / nst, rstd1 = rsqrtf((s2b - s1b * s1b / nst) / (nst - 1.0f));
    const float mean2 = s1c / nst, rstd2 = rsqrtf((s2c - s1c * s1c / nst) / (nst - 1.0f));
    // stage normalized xf tiles (once per block)
    for (int q = t; q < 42 * 11; q += 256) {
        int row = q / 11, cg = q % 11;
        int gr = min(y0 + row, 255), gc = min(x0 + cg * 4, 252);
        int go = gr * 256 + gc;
        int lo = row * 44 + cg * 4;
        int4 mv = *(const int4*)(mask + (size_t)b * HWc + go);
        float m0 = (float)mv.x, m1 = (float)mv.y, m2 = (float)mv.z, m3 = (float)mv.w;
        float4 v0 = *(const float4*)(xc + (size_t)(b * 3 + 0) * HWc + go);
        v0.x = (v0.x - mean0) * rstd0 * m0; v0.y = (v0.y - mean0) * rstd0 * m1;
        v0.z = (v0.z - mean0) * rstd0 * m2; v0.w = (v0.w - mean0) * rstd0 * m3;
        *(float4*)&f0in[lo] = v0;
        float4 v1 = *(const float4*)(xc + (size_t)(b * 3 + 1) * HWc + go);
        v1.x = (v1.x - mean1) * rstd1 * m0; v1.y = (v1.y - mean1) * rstd1 * m1;
        v1.z = (v1.z - mean1) * rstd1 * m2; v1.w = (v1.w - mean1) * rstd1 * m3;
        *(float4*)&f1in[lo] = v1;
        float4 v2 = *(const float4*)(xc + (size_t)(b * 3 + 2) * HWc + go);
        v2.x = (v2.x - mean2) * rstd2 * m0; v2.y = (v2.y - mean2) * rstd2 * m1;
        v2.z = (v2.z - mean2) * rstd2 * m2; v2.w = (v2.w - mean2) * rstd2 * m3;
        *(float4*)&f2in[lo] = v2;
    }
    // per-thread c-independent eval constants (named scalars)
    const int erow = t >> 3, ecg = t & 7;
    const int oy = y0 + erow;
    const int ox0 = x0 + ecg * 4;
    DECLJ(0) DECLJ(1) DECLJ(2) DECLJ(3)
    SETJ(0) SETJ(1) SETJ(2) SETJ(3)
    __syncthreads();
    const float* xb = x + (size_t)b * Cn * HWc;
    const int vrg = t / 11, vcg = t % 11, vcolo = vcg * 4;
    const int gcb = min(x0 + vcolo, 252);
    const bool vact = (t < 176);
    for (int c = c0; c < c1; ++c) {
        // ---- vertical pass ----
        if (vact) {
            const float* xp = xb + (size_t)c * HWc;
            float4 xA0 = f4z(), xQ0 = f4z(), p00 = f4z(), p10 = f4z(), p20 = f4z();
            float4 xA1 = f4z(), xQ1 = f4z(), p01 = f4z(), p11 = f4z(), p21 = f4z();
            VSTEP(0, 1, 0, G0, G0)  VSTEP(1, 1, 1, G1, G0)  VSTEP(2, 1, 1, G2, G1)
            VSTEP(3, 1, 1, G3, G2)  VSTEP(4, 1, 1, G4, G3)  VSTEP(5, 1, 1, G5, G4)
            VSTEP(6, 1, 1, G6, G5)  VSTEP(7, 1, 1, G7, G6)  VSTEP(8, 1, 1, G8, G7)
            VSTEP(9, 1, 1, G9, G8)  VSTEP(10, 1, 1, G10, G9) VSTEP(11, 0, 1, G0, G10)
            {
                float* dst = &vb5[(2 * vrg + 0) * 228 + vcolo * 5];
                *(float4*)&dst[0]  = make_float4(xA0.x, xQ0.x, p00.x, p10.x);
                *(float4*)&dst[4]  = make_float4(p20.x, xA0.y, xQ0.y, p00.y);
                *(float4*)&dst[8]  = make_float4(p10.y, p20.y, xA0.z, xQ0.z);
                *(float4*)&dst[12] = make_float4(p00.z, p10.z, p20.z, xA0.w);
                *(float4*)&dst[16] = make_float4(xQ0.w, p00.w, p10.w, p20.w);
            }
            {
                float* dst = &vb5[(2 * vrg + 1) * 228 + vcolo * 5];
                *(float4*)&dst[0]  = make_float4(xA1.x, xQ1.x, p01.x, p11.x);
                *(float4*)&dst[4]  = make_float4(p21.x, xA1.y, xQ1.y, p01.y);
                *(float4*)&dst[8]  = make_float4(p11.y, p21.y, xA1.z, xQ1.z);
                *(float4*)&dst[12] = make_float4(p01.z, p11.z, p21.z, xA1.w);
                *(float4*)&dst[16] = make_float4(xQ1.w, p01.w, p11.w, p21.w);
            }
        }
        __syncthreads();
        // ---- horizontal pass: 18 named b128 loads -> named accumulators ----
        {
            const float* src = &vb5[erow * 228 + ecg * 20];
            DECLH(0) DECLH(1) DECLH(2) DECLH(3)
            float4 L0 = *(const float4*)(src + 0);
            TM0(0, L0.x) TM0(1, L0.y) TM0(2, L0.z) TM0(3, L0.w)
            float4 L1 = *(const float4*)(src + 4);
            TM0(4, L1.x) TM1(0, L1.y) TM1(1, L1.z) TM1(2, L1.w)
            float4 L2 = *(const float4*)(src + 8);
            TM1(3, L2.x) TM1(4, L2.y) TM2(0, L2.z) TM2(1, L2.w)
            float4 L3 = *(const float4*)(src + 12);
            TM2(2, L3.x) TM2(3, L3.y) TM2(4, L3.z) TM3(0, L3.w)
            float4 L4 = *(const float4*)(src + 16);
            TM3(1, L4.x) TM3(2, L4.y) TM3(3, L4.z) TM3(4, L4.w)
            float4 L5 = *(const float4*)(src + 20);
            TM4(0, L5.x) TM4(1, L5.y) TM4(2, L5.z) TM4(3, L5.w)
            float4 L6 = *(const float4*)(src + 24);
            TM4(4, L6.x) TM5(0, L6.y) TM5(1, L6.z) TM5(2, L6.w)
            float4 L7 = *(const float4*)(src + 28);
            TM5(3, L7.x) TM5(4, L7.y) TM6(0, L7.z) TM6(1, L7.w)
            float4 L8 = *(const float4*)(src + 32);
            TM6(2, L8.x) TM6(3, L8.y) TM6(4, L8.z) TM7(0, L8.w)
            float4 L9 = *(const float4*)(src + 36);
            TM7(1, L9.x) TM7(2, L9.y) TM7(3, L9.z) TM7(4, L9.w)
            float4 L10 = *(const float4*)(src + 40);
            TM8(0, L10.x) TM8(1, L10.y) TM8(2, L10.z) TM8(3, L10.w)
            float4 L11 = *(const float4*)(src + 44);
            TM8(4, L11.x) TM9(0, L11.y) TM9(1, L11.z) TM9(2, L11.w)
            float4 L12 = *(const float4*)(src + 48);
            TM9(3, L12.x) TM9(4, L12.y) TM10(0, L12.z) TM10(1, L12.w)
            float4 L13 = *(const float4*)(src + 52);
            TM10(2, L13.x) TM10(3, L13.y) TM10(4, L13.z) TM11(0, L13.w)
            float4 L14 = *(const float4*)(src + 56);
            TM11(1, L14.x) TM11(2, L14.y) TM11(3, L14.z) TM11(4, L14.w)
            float4 L15 = *(const float4*)(src + 60);
            TM12(0, L15.x) TM12(1, L15.y) TM12(2, L15.z) TM12(3, L15.w)
            float4 L16 = *(const float4*)(src + 64);
            TM12(4, L16.x) TM13(0, L16.y) TM13(1, L16.z) TM13(2, L16.w)
            float4 L17 = *(const float4*)(src + 68);
            TM13(3, L17.x) TM13(4, L17.y)
            float sa0 = 0.f, sa1 = 0.f, sa2 = 0.f;
            SSIMJ(0) SSIMJ(1) SSIMJ(2) SSIMJ(3)
            sa0 = wave_sum64(sa0);
            sa1 = wave_sum64(sa1);
            sa2 = wave_sum64(sa2);
            if ((t & 63) == 63) {
                atomicAdd(&ssum[(b * 3 + 0) * 64 + c], sa0);
                atomicAdd(&ssum[(b * 3 + 1) * 64 + c], sa1);
                atomicAdd(&ssum[(b * 3 + 2) * 64 + c], sa2);
            }
        }
        __syncthreads();   // vb5 consumed before next vertical overwrites
    }
}

// K6: normalize ssim sums -> ssim_info output; conv3 over C + MLP head -> h output
__global__ __launch_bounds__(512) void k6_head(const float* __restrict__ ssum, const float* __restrict__ cw,
                                               const float* __restrict__ w1, const float* __restrict__ b1,
                                               const float* __restrict__ w2, const float* __restrict__ b2,
                                               float* __restrict__ out) {
    __shared__ float si[1536];
    __shared__ float h0[512];
    __shared__ float h1[512];
    const int t = threadIdx.x;
    const float inv = 1.0f / (float)HPWPc;
    for (int idx = t; idx < 1536; idx += 512) {
        float v = ssum[idx] * inv;
        si[idx] = v;
        out[512 + idx] = v;
    }
    __syncthreads();
    const int b = t >> 6, y = t & 63;
    float acc = 0.f;
#pragma unroll
    for (int i = 0; i < 3; ++i) {
#pragma unroll
        for (int kh = 0; kh < 3; ++kh) {
            int yy = y + kh - 1;
            if (yy >= 0 && yy < 64) acc = fmaf(si[(b * 3 + i) * 64 + yy], cw[i * 3 + kh], acc);
        }
    }
    h0[t] = fmaxf(acc, 0.f);
    __syncthreads();
    float a1 = b1[y];
    for (int c = 0; c < 64; ++c) a1 = fmaf(h0[(b << 6) + c], w1[(y << 6) + c], a1);
    h1[t] = fmaxf(a1, 0.f);
    __syncthreads();
    float a2 = b2[y];
    for (int c = 0; c < 64; ++c) a2 = fmaf(h1[(b << 6) + c], w2[(y << 6) + c], a2);
    out[t] = 1.f / (1.f + expf(-a2));
}

extern "C" void kernel_launch(void* const* d_in, const int* in_sizes, int n_in,
                              void* d_out, int out_size, void* d_ws, size_t ws_size,
                              hipStream_t stream) {
    const float* x      = (const float*)d_in[0];
    const int*   mask   = (const int*)d_in[1];
    const float* conv_w = (const float*)d_in[2];
    const float* w1     = (const float*)d_in[3];
    const float* b1     = (const float*)d_in[4];
    const float* w2     = (const float*)d_in[5];
    const float* b2     = (const float*)d_in[6];
    float* out = (float*)d_out;

    float* wsf   = (float*)d_ws;
    float* stats = wsf;                       // 64 floats (8 b x 8 slots)
    float* ssum  = wsf + 64;                  // 1536 floats
    float* xcf   = wsf + 1600;                // 8*3*65536 raw xc (max/mean/min)
    float* muf   = xcf + (size_t)Bn * 3 * HWc;      // 8*3*60516
    float* ef2   = muf + (size_t)Bn * 3 * HPWPc;    // 8*3*60516

    hipMemsetAsync(d_ws, 0, 6400, stream);  // stats + ssum accumulators

    k1_stats<<<dim3(64, 8), 256, 0, stream>>>(x, mask, xcf, stats);
    k4_blur3<<<dim3(8, 8, 24), 256, 0, stream>>>(xcf, mask, stats, muf, ef2);
    k5_main<<<dim3(8, 8, 24), 256, 0, stream>>>(x, xcf, mask, stats, muf, ef2, ssum);
    k6_head<<<1, 512, 0, stream>>>(ssum, conv_w, w1, b1, w2, b2, out);
}

// Round 5
// 666.906 us; speedup vs baseline: 2.9697x; 2.7555x over previous
//
#include <hip/hip_runtime.h>
#include <cmath>

#define Bn   8
#define Cn   64
#define HWc  65536      // 256*256
#define HPc  246        // 256-11+1
#define HPWPc 60516     // 246*246
#define C1v  0.01f      // (0.01*10)^2
#define C2v  0.09f      // (0.03*10)^2

// 11-tap normalized gaussian, sigma=1.5 (double, then f32 cast — matches numpy)
static __device__ __forceinline__ void gauss11(float* gw) {
    double gg[11]; double s = 0.0;
#pragma unroll
    for (int j = 0; j < 11; ++j) { double d = (double)(j - 5); gg[j] = exp(-(d * d) / 4.5); s += gg[j]; }
#pragma unroll
    for (int j = 0; j < 11; ++j) gw[j] = (float)(gg[j] / s);
}

static __device__ __forceinline__ float4 f4z() { return make_float4(0.f, 0.f, 0.f, 0.f); }
static __device__ __forceinline__ float4 f4scale(float g, const float4 v) {
    return make_float4(g * v.x, g * v.y, g * v.z, g * v.w);
}
static __device__ __forceinline__ void f4add(float4& a, const float4 v) {
    a.x += v.x; a.y += v.y; a.z += v.z; a.w += v.w;
}
static __device__ __forceinline__ void f4fma(float4& a, const float4 u, const float4 v) {
    a.x = fmaf(u.x, v.x, a.x); a.y = fmaf(u.y, v.y, a.y);
    a.z = fmaf(u.z, v.z, a.z); a.w = fmaf(u.w, v.w, a.w);
}

// wave64 sum via DPP (VALU pipe, no LDS traffic). Result valid in lane 63.
static __device__ __forceinline__ float wave_sum64(float v) {
    v += __int_as_float(__builtin_amdgcn_update_dpp(0, __float_as_int(v), 0x111, 0xf, 0xf, true)); // row_shr:1
    v += __int_as_float(__builtin_amdgcn_update_dpp(0, __float_as_int(v), 0x112, 0xf, 0xf, true)); // row_shr:2
    v += __int_as_float(__builtin_amdgcn_update_dpp(0, __float_as_int(v), 0x114, 0xf, 0xf, true)); // row_shr:4
    v += __int_as_float(__builtin_amdgcn_update_dpp(0, __float_as_int(v), 0x118, 0xf, 0xf, true)); // row_shr:8
    v += __int_as_float(__builtin_amdgcn_update_dpp(0, __float_as_int(v), 0x142, 0xf, 0xf, true)); // row_bcast:15
    v += __int_as_float(__builtin_amdgcn_update_dpp(0, __float_as_int(v), 0x143, 0xf, 0xf, true)); // row_bcast:31
    return v;
}

// K1: channel max/mean/min (-> xcf planes, RAW) + masked stats atomics
__global__ __launch_bounds__(256) void k1_stats(const float* __restrict__ x, const int* __restrict__ mask,
                                                float* __restrict__ xcf, float* __restrict__ stats) {
    const int b = blockIdx.y;
    const int p0 = blockIdx.x * 1024 + threadIdx.x * 4;
    const float4* xp = (const float4*)(x + (size_t)b * Cn * HWc) + (p0 >> 2);
    float4 v = xp[0];
    float4 vmax = v, vmin = v, vsum = v;
#pragma unroll 4
    for (int c = 1; c < Cn; ++c) {
        float4 u = xp[(size_t)c * (HWc / 4)];
        vmax.x = fmaxf(vmax.x, u.x); vmax.y = fmaxf(vmax.y, u.y);
        vmax.z = fmaxf(vmax.z, u.z); vmax.w = fmaxf(vmax.w, u.w);
        vmin.x = fminf(vmin.x, u.x); vmin.y = fminf(vmin.y, u.y);
        vmin.z = fminf(vmin.z, u.z); vmin.w = fminf(vmin.w, u.w);
        vsum.x += u.x; vsum.y += u.y; vsum.z += u.z; vsum.w += u.w;
    }
    float4 vmean = make_float4(vsum.x * (1.f / 64.f), vsum.y * (1.f / 64.f),
                               vsum.z * (1.f / 64.f), vsum.w * (1.f / 64.f));
    *(float4*)(xcf + (size_t)(b * 3 + 0) * HWc + p0) = vmax;
    *(float4*)(xcf + (size_t)(b * 3 + 1) * HWc + p0) = vmean;
    *(float4*)(xcf + (size_t)(b * 3 + 2) * HWc + p0) = vmin;
    int4 mv = *(const int4*)(mask + (size_t)b * HWc + p0);
    float m0 = (float)mv.x, m1 = (float)mv.y, m2 = (float)mv.z, m3 = (float)mv.w;
    float r[7];
    r[0] = m0 + m1 + m2 + m3;
    r[1] = vmax.x * m0 + vmax.y * m1 + vmax.z * m2 + vmax.w * m3;
    r[2] = vmean.x * m0 + vmean.y * m1 + vmean.z * m2 + vmean.w * m3;
    r[3] = vmin.x * m0 + vmin.y * m1 + vmin.z * m2 + vmin.w * m3;
    r[4] = vmax.x * vmax.x * m0 + vmax.y * vmax.y * m1 + vmax.z * vmax.z * m2 + vmax.w * vmax.w * m3;
    r[5] = vmean.x * vmean.x * m0 + vmean.y * vmean.y * m1 + vmean.z * vmean.z * m2 + vmean.w * vmean.w * m3;
    r[6] = vmin.x * vmin.x * m0 + vmin.y * vmin.y * m1 + vmin.z * vmin.z * m2 + vmin.w * vmin.w * m3;
#pragma unroll
    for (int k = 0; k < 7; ++k) {
        float vv = wave_sum64(r[k]);
        if ((threadIdx.x & 63) == 63) atomicAdd(&stats[b * 8 + k], vv);
    }
}

// K4: mu_f = blur(xf), ef2 = blur(xf^2); xf computed inline from raw xc + mask + stats.
__global__ __launch_bounds__(256) void k4_blur3(const float* __restrict__ xc, const int* __restrict__ mask,
                                                const float* __restrict__ stats,
                                                float* __restrict__ muf, float* __restrict__ ef2g) {
    __shared__ __align__(16) float vb2[32 * 92];
    const int t = threadIdx.x;
    const int bi = blockIdx.z, b = bi / 3, i = bi % 3;
    const int y0 = blockIdx.y * 32, x0 = blockIdx.x * 32;
    float gw[11]; gauss11(gw);
    const float nst = stats[b * 8 + 0];
    const float s1 = stats[b * 8 + 1 + i], s2 = stats[b * 8 + 4 + i];
    const float mean = s1 / nst;
    const float rstd = rsqrtf((s2 - s1 * s1 / nst) / (nst - 1.0f));
    if (t < 176) {
        const int rg = t / 11, cg = t % 11, colo = cg * 4;
        const int gcb = min(x0 + colo, 252);
        const float* xp = xc + (size_t)bi * HWc;
        const int* mp = mask + (size_t)b * HWc;
        float4 av0 = f4z(), ab0 = f4z(), av1 = f4z(), ab1 = f4z();
#pragma unroll
        for (int k = 0; k < 12; ++k) {
            int gr = min(y0 + 2 * rg + k, 255);
            float4 v = *(const float4*)(xp + gr * 256 + gcb);
            int4 mv = *(const int4*)(mp + gr * 256 + gcb);
            float4 f;
            f.x = (v.x - mean) * rstd * (float)mv.x;
            f.y = (v.y - mean) * rstd * (float)mv.y;
            f.z = (v.z - mean) * rstd * (float)mv.z;
            f.w = (v.w - mean) * rstd * (float)mv.w;
            if (k <= 10) { float4 tv = f4scale(gw[k], f); f4add(av0, tv); f4fma(ab0, tv, f); }
            if (k >= 1)  { float4 tv = f4scale(gw[k - 1], f); f4add(av1, tv); f4fma(ab1, tv, f); }
        }
        {
            float* dst = &vb2[(2 * rg + 0) * 92 + colo * 2];
            *(float4*)&dst[0] = make_float4(av0.x, ab0.x, av0.y, ab0.y);
            *(float4*)&dst[4] = make_float4(av0.z, ab0.z, av0.w, ab0.w);
        }
        {
            float* dst = &vb2[(2 * rg + 1) * 92 + colo * 2];
            *(float4*)&dst[0] = make_float4(av1.x, ab1.x, av1.y, ab1.y);
            *(float4*)&dst[4] = make_float4(av1.z, ab1.z, av1.w, ab1.w);
        }
    }
    __syncthreads();
    {
        const int erow = t >> 3, ecg = t & 7;
        const int oy = y0 + erow;
        const float* src = &vb2[erow * 92 + ecg * 8];
        float a00 = 0.f, a01 = 0.f, a02 = 0.f, a03 = 0.f;
        float a10 = 0.f, a11 = 0.f, a12 = 0.f, a13 = 0.f;
#pragma unroll
        for (int m = 0; m < 14; ++m) {
            float v0 = src[m * 2 + 0];
            float v1 = src[m * 2 + 1];
#pragma unroll
            for (int j = 0; j < 4; ++j) {
                const int kk = m - j;
                if (kk >= 0 && kk <= 10) {
                    if (j == 0) { a00 = fmaf(gw[kk], v0, a00); a10 = fmaf(gw[kk], v1, a10); }
                    if (j == 1) { a01 = fmaf(gw[kk], v0, a01); a11 = fmaf(gw[kk], v1, a11); }
                    if (j == 2) { a02 = fmaf(gw[kk], v0, a02); a12 = fmaf(gw[kk], v1, a12); }
                    if (j == 3) { a03 = fmaf(gw[kk], v0, a03); a13 = fmaf(gw[kk], v1, a13); }
                }
            }
        }
        if (oy < HPc) {
            size_t ob = (size_t)bi * HPWPc + (size_t)oy * HPc;
            int oxb = x0 + ecg * 4;
            if (oxb + 0 < HPc) { muf[ob + oxb + 0] = a00; ef2g[ob + oxb + 0] = a10; }
            if (oxb + 1 < HPc) { muf[ob + oxb + 1] = a01; ef2g[ob + oxb + 1] = a11; }
            if (oxb + 2 < HPc) { muf[ob + oxb + 2] = a02; ef2g[ob + oxb + 2] = a12; }
            if (oxb + 3 < HPc) { muf[ob + oxb + 3] = a03; ef2g[ob + oxb + 3] = a13; }
        }
    }
}

// ---- K5 macro machinery (no local arrays; minimal persistent registers) ----
#define T(F,J,KK,V) h##F##_##J = fmaf(G##KK, (V), h##F##_##J);
#define TM0(F,V)  T(F,0,0,V)
#define TM1(F,V)  T(F,0,1,V) T(F,1,0,V)
#define TM2(F,V)  T(F,0,2,V) T(F,1,1,V) T(F,2,0,V)
#define TM3(F,V)  T(F,0,3,V) T(F,1,2,V) T(F,2,1,V) T(F,3,0,V)
#define TM4(F,V)  T(F,0,4,V) T(F,1,3,V) T(F,2,2,V) T(F,3,1,V)
#define TM5(F,V)  T(F,0,5,V) T(F,1,4,V) T(F,2,3,V) T(F,3,2,V)
#define TM6(F,V)  T(F,0,6,V) T(F,1,5,V) T(F,2,4,V) T(F,3,3,V)
#define TM7(F,V)  T(F,0,7,V) T(F,1,6,V) T(F,2,5,V) T(F,3,4,V)
#define TM8(F,V)  T(F,0,8,V) T(F,1,7,V) T(F,2,6,V) T(F,3,5,V)
#define TM9(F,V)  T(F,0,9,V) T(F,1,8,V) T(F,2,7,V) T(F,3,6,V)
#define TM10(F,V) T(F,0,10,V) T(F,1,9,V) T(F,2,8,V) T(F,3,7,V)
#define TM11(F,V) T(F,1,10,V) T(F,2,9,V) T(F,3,8,V)
#define TM12(F,V) T(F,2,10,V) T(F,3,9,V)
#define TM13(F,V) T(F,3,10,V)

#define DECLH(J) float h0_##J = 0.f, h1_##J = 0.f, h2_##J = 0.f, h3_##J = 0.f, h4_##J = 0.f;
// persistent per-thread constants: M = mu1, S = (s1 + C2) or +inf (invalid marker)
#define DECLJ(J) float M0_##J, M1_##J, M2_##J, S0_##J, S1_##J, S2_##J;
#define SETI(I,J) { float mu1 = 0.f, e2 = 0.f; \
    if (vld) { size_t o = (size_t)(b * 3 + I) * HPWPc + (size_t)oy * HPc + ox; mu1 = muf[o]; e2 = ef2g[o]; } \
    M##I##_##J = mu1; S##I##_##J = vld ? ((e2 - mu1 * mu1) + C2v) : __builtin_inff(); }
#define SETJ(J) { int ox = ox0 + J; bool vld = (oy < HPc) && (ox < HPc); \
    SETI(0,J) SETI(1,J) SETI(2,J) }

#define SSIMI(I,J,HV) { float am = M##I##_##J * m2; \
    float num = fmaf(2.f, am, C1v) * fmaf(2.f, (HV) - am, C2v); \
    float den = fmaf(M##I##_##J, M##I##_##J, c1m2) * (S##I##_##J + s2); \
    sa##I += num * __builtin_amdgcn_rcpf(den); }
#define SSIMJ(J) { float m2 = h0_##J; float m2sq = m2 * m2; \
    float c1m2 = C1v + m2sq; float s2 = h1_##J - m2sq; \
    SSIMI(0,J,h2_##J) SSIMI(1,J,h3_##J) SSIMI(2,J,h4_##J) }

#define VSTEP(K, DOA, DOB, GA, GB) { \
    int gr = y0 + 2 * vrg + (K); gr = (gr > 255) ? 255 : gr; \
    float4 xv = *(const float4*)(xp + gr * 256 + gcb); \
    const int ro = (2 * vrg + (K)) * 44 + vcolo; \
    float4 f0 = *(const float4*)&f0in[ro]; \
    float4 f1v = *(const float4*)&f1in[ro]; \
    float4 f2v = *(const float4*)&f2in[ro]; \
    if (DOA) { float4 tv = f4scale((GA), xv); f4add(xA0, tv); f4fma(xQ0, tv, xv); \
               f4fma(p00, tv, f0); f4fma(p10, tv, f1v); f4fma(p20, tv, f2v); } \
    if (DOB) { float4 tv = f4scale((GB), xv); f4add(xA1, tv); f4fma(xQ1, tv, xv); \
               f4fma(p01, tv, f0); f4fma(p11, tv, f1v); f4fma(p21, tv, f2v); } }

// K5: per (b, 32x32 tile): xf tiles staged in LDS once; full c-loop (64 channels).
// __launch_bounds__(256,2): 128-VGPR budget — (256,3) forces an ~85-reg budget and
// the allocator spills ~100 floats/thread/iter to scratch (R2-R4: 6.7 GB HBM traffic).
__global__ __launch_bounds__(256, 2) void k5_main(const float* __restrict__ x, const float* __restrict__ xc,
                                                  const int* __restrict__ mask, const float* __restrict__ stats,
                                                  const float* __restrict__ muf, const float* __restrict__ ef2g,
                                                  float* __restrict__ ssum) {
    __shared__ __align__(16) float f0in[42 * 44];
    __shared__ __align__(16) float f1in[42 * 44];
    __shared__ __align__(16) float f2in[42 * 44];
    __shared__ __align__(16) float vb5[32 * 228];
    const int t = threadIdx.x;
    const int b = blockIdx.z;
    const int y0 = blockIdx.y * 32, x0 = blockIdx.x * 32;
    // gauss weights as named scalars (same numerics as gauss11)
    const double e0 = exp(-25.0 / 4.5), e1 = exp(-16.0 / 4.5), e2d = exp(-9.0 / 4.5),
                 e3 = exp(-4.0 / 4.5), e4 = exp(-1.0 / 4.5);
    const double sg = 1.0 + 2.0 * (e0 + e1 + e2d + e3 + e4);
    const float G0 = (float)(e0 / sg), G1 = (float)(e1 / sg), G2 = (float)(e2d / sg),
                G3 = (float)(e3 / sg), G4 = (float)(e4 / sg), G5 = (float)(1.0 / sg);
    const float G6 = G4, G7 = G3, G8 = G2, G9 = G1, G10 = G0;
    // per-(b,i) normalization constants
    const float nst = stats[b * 8 + 0];
    const float s1a = stats[b * 8 + 1], s2a = stats[b * 8 + 4];
    const float s1b = stats[b * 8 + 2], s2b = stats[b * 8 + 5];
    const float s1c = stats[b * 8 + 3], s2c = stats[b * 8 + 6];
    const float mean0 = s1a / nst, rstd0 = rsqrtf((s2a - s1a * s1a / nst) / (nst - 1.0f));
    const float mean1 = s1b / nst, rstd1 = rsqrtf((s2b - s1b * s1b / nst) / (nst - 1.0f));
    const float mean2 = s1c / nst, rstd2 = rsqrtf((s2c - s1c * s1c / nst) / (nst - 1.0f));
    // stage normalized xf tiles (once per block)
    for (int q = t; q < 42 * 11; q += 256) {
        int row = q / 11, cg = q % 11;
        int gr = min(y0 + row, 255), gc = min(x0 + cg * 4, 252);
        int go = gr * 256 + gc;
        int lo = row * 44 + cg * 4;
        int4 mv = *(const int4*)(mask + (size_t)b * HWc + go);
        float m0 = (float)mv.x, m1 = (float)mv.y, m2 = (float)mv.z, m3 = (float)mv.w;
        float4 v0 = *(const float4*)(xc + (size_t)(b * 3 + 0) * HWc + go);
        v0.x = (v0.x - mean0) * rstd0 * m0; v0.y = (v0.y - mean0) * rstd0 * m1;
        v0.z = (v0.z - mean0) * rstd0 * m2; v0.w = (v0.w - mean0) * rstd0 * m3;
        *(float4*)&f0in[lo] = v0;
        float4 v1 = *(const float4*)(xc + (size_t)(b * 3 + 1) * HWc + go);
        v1.x = (v1.x - mean1) * rstd1 * m0; v1.y = (v1.y - mean1) * rstd1 * m1;
        v1.z = (v1.z - mean1) * rstd1 * m2; v1.w = (v1.w - mean1) * rstd1 * m3;
        *(float4*)&f1in[lo] = v1;
        float4 v2 = *(const float4*)(xc + (size_t)(b * 3 + 2) * HWc + go);
        v2.x = (v2.x - mean2) * rstd2 * m0; v2.y = (v2.y - mean2) * rstd2 * m1;
        v2.z = (v2.z - mean2) * rstd2 * m2; v2.w = (v2.w - mean2) * rstd2 * m3;
        *(float4*)&f2in[lo] = v2;
    }
    // per-thread c-independent eval constants (named scalars, 24 persistent regs)
    const int erow = t >> 3, ecg = t & 7;
    const int oy = y0 + erow;
    const int ox0 = x0 + ecg * 4;
    DECLJ(0) DECLJ(1) DECLJ(2) DECLJ(3)
    SETJ(0) SETJ(1) SETJ(2) SETJ(3)
    __syncthreads();
    const float* xb = x + (size_t)b * Cn * HWc;
    const int vrg = t / 11, vcg = t % 11, vcolo = vcg * 4;
    const int gcb = min(x0 + vcolo, 252);
    const bool vact = (t < 176);
    for (int c = 0; c < Cn; ++c) {
        // ---- vertical pass ----
        if (vact) {
            const float* xp = xb + (size_t)c * HWc;
            float4 xA0 = f4z(), xQ0 = f4z(), p00 = f4z(), p10 = f4z(), p20 = f4z();
            float4 xA1 = f4z(), xQ1 = f4z(), p01 = f4z(), p11 = f4z(), p21 = f4z();
            VSTEP(0, 1, 0, G0, G0)  VSTEP(1, 1, 1, G1, G0)  VSTEP(2, 1, 1, G2, G1)
            VSTEP(3, 1, 1, G3, G2)  VSTEP(4, 1, 1, G4, G3)  VSTEP(5, 1, 1, G5, G4)
            VSTEP(6, 1, 1, G6, G5)  VSTEP(7, 1, 1, G7, G6)  VSTEP(8, 1, 1, G8, G7)
            VSTEP(9, 1, 1, G9, G8)  VSTEP(10, 1, 1, G10, G9) VSTEP(11, 0, 1, G0, G10)
            {
                float* dst = &vb5[(2 * vrg + 0) * 228 + vcolo * 5];
                *(float4*)&dst[0]  = make_float4(xA0.x, xQ0.x, p00.x, p10.x);
                *(float4*)&dst[4]  = make_float4(p20.x, xA0.y, xQ0.y, p00.y);
                *(float4*)&dst[8]  = make_float4(p10.y, p20.y, xA0.z, xQ0.z);
                *(float4*)&dst[12] = make_float4(p00.z, p10.z, p20.z, xA0.w);
                *(float4*)&dst[16] = make_float4(xQ0.w, p00.w, p10.w, p20.w);
            }
            {
                float* dst = &vb5[(2 * vrg + 1) * 228 + vcolo * 5];
                *(float4*)&dst[0]  = make_float4(xA1.x, xQ1.x, p01.x, p11.x);
                *(float4*)&dst[4]  = make_float4(p21.x, xA1.y, xQ1.y, p01.y);
                *(float4*)&dst[8]  = make_float4(p11.y, p21.y, xA1.z, xQ1.z);
                *(float4*)&dst[12] = make_float4(p01.z, p11.z, p21.z, xA1.w);
                *(float4*)&dst[16] = make_float4(xQ1.w, p01.w, p11.w, p21.w);
            }
        }
        __syncthreads();
        // ---- horizontal pass: 18 named b128 loads -> named accumulators ----
        {
            const float* src = &vb5[erow * 228 + ecg * 20];
            DECLH(0) DECLH(1) DECLH(2) DECLH(3)
            float4 L0 = *(const float4*)(src + 0);
            TM0(0, L0.x) TM0(1, L0.y) TM0(2, L0.z) TM0(3, L0.w)
            float4 L1 = *(const float4*)(src + 4);
            TM0(4, L1.x) TM1(0, L1.y) TM1(1, L1.z) TM1(2, L1.w)
            float4 L2 = *(const float4*)(src + 8);
            TM1(3, L2.x) TM1(4, L2.y) TM2(0, L2.z) TM2(1, L2.w)
            float4 L3 = *(const float4*)(src + 12);
            TM2(2, L3.x) TM2(3, L3.y) TM2(4, L3.z) TM3(0, L3.w)
            float4 L4 = *(const float4*)(src + 16);
            TM3(1, L4.x) TM3(2, L4.y) TM3(3, L4.z) TM3(4, L4.w)
            float4 L5 = *(const float4*)(src + 20);
            TM4(0, L5.x) TM4(1, L5.y) TM4(2, L5.z) TM4(3, L5.w)
            float4 L6 = *(const float4*)(src + 24);
            TM4(4, L6.x) TM5(0, L6.y) TM5(1, L6.z) TM5(2, L6.w)
            float4 L7 = *(const float4*)(src + 28);
            TM5(3, L7.x) TM5(4, L7.y) TM6(0, L7.z) TM6(1, L7.w)
            float4 L8 = *(const float4*)(src + 32);
            TM6(2, L8.x) TM6(3, L8.y) TM6(4, L8.z) TM7(0, L8.w)
            float4 L9 = *(const float4*)(src + 36);
            TM7(1, L9.x) TM7(2, L9.y) TM7(3, L9.z) TM7(4, L9.w)
            float4 L10 = *(const float4*)(src + 40);
            TM8(0, L10.x) TM8(1, L10.y) TM8(2, L10.z) TM8(3, L10.w)
            float4 L11 = *(const float4*)(src + 44);
            TM8(4, L11.x) TM9(0, L11.y) TM9(1, L11.z) TM9(2, L11.w)
            float4 L12 = *(const float4*)(src + 48);
            TM9(3, L12.x) TM9(4, L12.y) TM10(0, L12.z) TM10(1, L12.w)
            float4 L13 = *(const float4*)(src + 52);
            TM10(2, L13.x) TM10(3, L13.y) TM10(4, L13.z) TM11(0, L13.w)
            float4 L14 = *(const float4*)(src + 56);
            TM11(1, L14.x) TM11(2, L14.y) TM11(3, L14.z) TM11(4, L14.w)
            float4 L15 = *(const float4*)(src + 60);
            TM12(0, L15.x) TM12(1, L15.y) TM12(2, L15.z) TM12(3, L15.w)
            float4 L16 = *(const float4*)(src + 64);
            TM12(4, L16.x) TM13(0, L16.y) TM13(1, L16.z) TM13(2, L16.w)
            float4 L17 = *(const float4*)(src + 68);
            TM13(3, L17.x) TM13(4, L17.y)
            float sa0 = 0.f, sa1 = 0.f, sa2 = 0.f;
            SSIMJ(0) SSIMJ(1) SSIMJ(2) SSIMJ(3)
            sa0 = wave_sum64(sa0);
            sa1 = wave_sum64(sa1);
            sa2 = wave_sum64(sa2);
            if ((t & 63) == 63) {
                atomicAdd(&ssum[(b * 3 + 0) * 64 + c], sa0);
                atomicAdd(&ssum[(b * 3 + 1) * 64 + c], sa1);
                atomicAdd(&ssum[(b * 3 + 2) * 64 + c], sa2);
            }
        }
        __syncthreads();   // vb5 consumed before next vertical overwrites
    }
}

// K6: normalize ssim sums -> ssim_info output; conv3 over C + MLP head -> h output
__global__ __launch_bounds__(512) void k6_head(const float* __restrict__ ssum, const float* __restrict__ cw,
                                               const float* __restrict__ w1, const float* __restrict__ b1,
                                               const float* __restrict__ w2, const float* __restrict__ b2,
                                               float* __restrict__ out) {
    __shared__ float si[1536];
    __shared__ float h0[512];
    __shared__ float h1[512];
    const int t = threadIdx.x;
    const float inv = 1.0f / (float)HPWPc;
    for (int idx = t; idx < 1536; idx += 512) {
        float v = ssum[idx] * inv;
        si[idx] = v;
        out[512 + idx] = v;
    }
    __syncthreads();
    const int b = t >> 6, y = t & 63;
    float acc = 0.f;
#pragma unroll
    for (int i = 0; i < 3; ++i) {
#pragma unroll
        for (int kh = 0; kh < 3; ++kh) {
            int yy = y + kh - 1;
            if (yy >= 0 && yy < 64) acc = fmaf(si[(b * 3 + i) * 64 + yy], cw[i * 3 + kh], acc);
        }
    }
    h0[t] = fmaxf(acc, 0.f);
    __syncthreads();
    float a1 = b1[y];
    for (int c = 0; c < 64; ++c) a1 = fmaf(h0[(b << 6) + c], w1[(y << 6) + c], a1);
    h1[t] = fmaxf(a1, 0.f);
    __syncthreads();
    float a2 = b2[y];
    for (int c = 0; c < 64; ++c) a2 = fmaf(h1[(b << 6) + c], w2[(y << 6) + c], a2);
    out[t] = 1.f / (1.f + expf(-a2));
}

extern "C" void kernel_launch(void* const* d_in, const int* in_sizes, int n_in,
                              void* d_out, int out_size, void* d_ws, size_t ws_size,
                              hipStream_t stream) {
    const float* x      = (const float*)d_in[0];
    const int*   mask   = (const int*)d_in[1];
    const float* conv_w = (const float*)d_in[2];
    const float* w1     = (const float*)d_in[3];
    const float* b1     = (const float*)d_in[4];
    const float* w2     = (const float*)d_in[5];
    const float* b2     = (const float*)d_in[6];
    float* out = (float*)d_out;

    float* wsf   = (float*)d_ws;
    float* stats = wsf;                       // 64 floats (8 b x 8 slots)
    float* ssum  = wsf + 64;                  // 1536 floats
    float* xcf   = wsf + 1600;                // 8*3*65536 raw xc (max/mean/min)
    float* muf   = xcf + (size_t)Bn * 3 * HWc;      // 8*3*60516
    float* ef2   = muf + (size_t)Bn * 3 * HPWPc;    // 8*3*60516

    hipMemsetAsync(d_ws, 0, 6400, stream);  // stats + ssum accumulators

    k1_stats<<<dim3(64, 8), 256, 0, stream>>>(x, mask, xcf, stats);
    k4_blur3<<<dim3(8, 8, 24), 256, 0, stream>>>(xcf, mask, stats, muf, ef2);
    k5_main<<<dim3(8, 8, 8), 256, 0, stream>>>(x, xcf, mask, stats, muf, ef2, ssum);
    k6_head<<<1, 512, 0, stream>>>(ssum, conv_w, w1, b1, w2, b2, out);
}